// Round 3
// baseline (371.343 us; speedup 1.0000x reference)
//
#include <hip/hip_runtime.h>
#include <math.h>

#define DD   2048
#define TEMP 0.07f
#define GRID_MAIN 1024
#define NROWS 16          // feature rows per block
#define DC    128         // k-chunk per LDS stage
#define KW    512         // k-range per wave
#define NCHW  (KW / DC)   // 4 chunks per wave

typedef __attribute__((ext_vector_type(8))) short short8;
typedef __attribute__((ext_vector_type(4))) float f32x4;

// ws layout (float offsets):
//   fA   [65536]  (131072 ushort: f in MFMA A-frag order [qt][ksg][lane][j])
//   blab [64]     at 65536 (int)
//   Wm   [1024*64] at 65600
//   Ws   [1024*64] at 131136
//   Wp   [1024*64] at 196672

__device__ __forceinline__ unsigned short to_bf16(float x) {
    union { float f; unsigned u; } v; v.f = x;
    unsigned r = v.u + 0x7fffu + ((v.u >> 16) & 1u);   // RNE
    return (unsigned short)(r >> 16);
}

// K0: f [64][2048] fp32 -> fA bf16 in A-fragment order; gather batch labels.
// A-frag (16x16x32): m = lane&15, k = ksg*32 + (lane>>4)*8 + j
__global__ __launch_bounds__(256) void k_prep(const float* __restrict__ f,
                                              const int* __restrict__ indexes,
                                              const int* __restrict__ labels,
                                              unsigned short* __restrict__ fA,
                                              int* __restrict__ blab) {
    const int q  = blockIdx.x;    // 0..63
    const int kc = threadIdx.x;   // k = kc*8
    const float* src = f + (size_t)q * DD + kc * 8;
    float4 a = *(const float4*)src;
    float4 b = *(const float4*)(src + 4);
    uint4 u;
    u.x = (unsigned)to_bf16(a.x) | ((unsigned)to_bf16(a.y) << 16);
    u.y = (unsigned)to_bf16(a.z) | ((unsigned)to_bf16(a.w) << 16);
    u.z = (unsigned)to_bf16(b.x) | ((unsigned)to_bf16(b.y) << 16);
    u.w = (unsigned)to_bf16(b.z) | ((unsigned)to_bf16(b.w) << 16);
    const int w = q >> 4, ksg = kc >> 2;
    const int lane = (q & 15) | ((kc & 3) << 4);
    *(uint4*)(fA + ((size_t)(w * 64 + ksg) * 64 + lane) * 8) = u;
    if (q == 0 && kc < 64) blab[kc] = labels[indexes[kc]];
}

// K1: per block: 16 feature rows, k split across waves (wave w owns k in
// [w*512, w*512+512)). Each wave is fully independent in the k-loop:
//  (a) aligned passthrough copy to out+1 (shuffle-realigned 16B stores)
//  (b) bf16 convert -> OWN LDS B-frag region (in-order same-wave DS, no barrier)
//  (c) MFMA vs all 4 q-tiles of fA (L2-hot) -> k-partial acc
// One __syncthreads at the end; waves sum k-partials via LDS (reusing Bf),
// then in-wave shfl_xor online reduce over the 16 rows -> per-block partials.
__global__ __launch_bounds__(256, 4) void k_main(const float* __restrict__ feat,
                                                 const unsigned short* __restrict__ fA,
                                                 const int* __restrict__ labels,
                                                 const int* __restrict__ blab,
                                                 float* __restrict__ out,
                                                 float* __restrict__ Wm,
                                                 float* __restrict__ Ws,
                                                 float* __restrict__ Wp) {
    __shared__ uint4 Bf[4][256];            // per-wave 4KB B-frag region; reused as accS
    __shared__ int lab_s[16], blab_s[64];

    const int tid = threadIdx.x;
    const int w   = tid >> 6;               // wave id = k-quarter
    const int l   = tid & 63;               // lane
    const int n0  = blockIdx.x * NROWS;

    if (tid < 16) lab_s[tid] = labels[n0 + tid];
    if (tid >= 64 && tid < 128) blab_s[tid - 64] = blab[tid - 64];

    const int rh = l >> 5;                  // row parity within pass
    const int c  = l & 31;                  // float4 column within 128-k chunk
    const int kw = w * KW;                  // wave k-base (floats)
    const uint4* __restrict__ fA4 = (const uint4*)fA;

    f32x4 acc[4];
#pragma unroll
    for (int qt = 0; qt < 4; ++qt) acc[qt] = (f32x4){0.f, 0.f, 0.f, 0.f};

    float4 Fa[8];
#pragma unroll
    for (int p = 0; p < 8; ++p)
        Fa[p] = *(const float4*)&feat[(size_t)(n0 + p * 2 + rh) * DD + kw + 4 * c];

    for (int ch = 0; ch < NCHW; ++ch) {
        const int k0 = kw + ch * DC;
#pragma unroll
        for (int p = 0; p < 8; ++p) {
            const int r = p * 2 + rh;
            float4 F = Fa[p];
            if (ch + 1 < NCHW)              // consume-replace prefetch (uniform branch)
                Fa[p] = *(const float4*)&feat[(size_t)(n0 + r) * DD + k0 + DC + 4 * c];
            // shuffle-realign: lane c stores {F.w, next.xyz} at 16B-aligned out
            float nx = __shfl_down(F.x, 1);
            float ny = __shfl_down(F.y, 1);
            float nz = __shfl_down(F.z, 1);
            size_t rowbase = (size_t)(n0 + r) * DD + k0;   // out[j] = feat[j-1]
            if (c < 31) {
                *(float4*)(out + rowbase + 4 * (c + 1)) = make_float4(F.w, nx, ny, nz);
            } else {
                out[rowbase + 128] = F.w;                  // chunk tail
            }
            if (c == 0) {                                  // chunk head (3 floats)
                out[rowbase + 1] = F.x;
                out[rowbase + 2] = F.y;
                out[rowbase + 3] = F.z;
            }
            // bf16 -> own-wave LDS B-frag: B[k][n], n=lane&15, k=(lane>>4)*8+j
            unsigned u0 = (unsigned)to_bf16(F.x) | ((unsigned)to_bf16(F.y) << 16);
            unsigned u1 = (unsigned)to_bf16(F.z) | ((unsigned)to_bf16(F.w) << 16);
            int ks    = c >> 3;
            int lanef = r | (((c >> 1) & 3) << 4);
            ((uint2*)&Bf[w][0])[(ks * 64 + lanef) * 2 + (c & 1)] = make_uint2(u0, u1);
        }
        // same-wave DS ops are in-order; lgkmcnt(0) guarantees writes landed
        // before the frag reads below (no cross-wave dependency -> no barrier)
        asm volatile("s_waitcnt lgkmcnt(0)" ::: "memory");
#pragma unroll
        for (int ks = 0; ks < 4; ++ks) {
            uint4 braw = Bf[w][ks * 64 + l];
            const int ksg = w * 16 + ch * 4 + ks;
#pragma unroll
            for (int qt = 0; qt < 4; ++qt) {
                uint4 araw = fA4[(size_t)(qt * 64 + ksg) * 64 + l];
                acc[qt] = __builtin_amdgcn_mfma_f32_16x16x32_bf16(
                    __builtin_bit_cast(short8, araw), __builtin_bit_cast(short8, braw),
                    acc[qt], 0, 0, 0);
            }
        }
    }

    // ---- combine k-partials across waves (reuse Bf LDS as accS) ----
    float* accS = (float*)&Bf[0][0];        // [src_wave][qt][reg][lane], 16 KB
#pragma unroll
    for (int qt = 0; qt < 4; ++qt)
#pragma unroll
        for (int r = 0; r < 4; ++r)
            accS[((w * 4 + qt) * 4 + r) * 64 + l] = acc[qt][r];
    __syncthreads();

    // wave w takes q-tile w: sum over 4 k-quarters, then masked online reduce
    // over the 16 feature rows (n = lane&15) via shfl_xor within 16-lane groups.
    const float invT = 1.0f / TEMP;
    const int nl = l & 15;
    const int g  = l >> 4;
    const int lab = lab_s[nl];
#pragma unroll
    for (int r = 0; r < 4; ++r) {
        float y = accS[((0 * 4 + w) * 4 + r) * 64 + l]
                + accS[((1 * 4 + w) * 4 + r) * 64 + l]
                + accS[((2 * 4 + w) * 4 + r) * 64 + l]
                + accS[((3 * 4 + w) * 4 + r) * 64 + l];
        y *= invT;
        const int q = w * 16 + g * 4 + r;
        const bool match = (lab == blab_s[q]);
        float M = match ? -3.4e38f : y;
        float S = match ? 0.f : 1.f;
        float P = match ? y : 3.4e38f;
#pragma unroll
        for (int d = 1; d < 16; d <<= 1) {
            float Mo = __shfl_xor(M, d, 64);
            float So = __shfl_xor(S, d, 64);
            float Po = __shfl_xor(P, d, 64);
            float Mn = fmaxf(M, Mo);
            S = S * __expf(M - Mn) + So * __expf(Mo - Mn);
            M = Mn;
            P = fminf(P, Po);
        }
        if (nl == 0) {
            Wm[blockIdx.x * 64 + q] = M;
            Ws[blockIdx.x * 64 + q] = S;
            Wp[blockIdx.x * 64 + q] = P;
        }
    }
}

// K2: combine 1024 partials/query -> loss at out[0]
__global__ __launch_bounds__(256) void k_loss(const float* __restrict__ Wm,
                                              const float* __restrict__ Ws,
                                              const float* __restrict__ Wp,
                                              float* __restrict__ out) {
    __shared__ float Lm[4][64], Ls[4][64], Lp[4][64];
    const int t = threadIdx.x, q = t & 63, ci = t >> 6;
    float M = -3.4e38f, S = 0.f, P = 3.4e38f;
    for (int i = ci * 256; i < ci * 256 + 256; ++i) {
        float m = Wm[i * 64 + q], s = Ws[i * 64 + q], p = Wp[i * 64 + q];
        if (m > M) { S = S * __expf(M - m) + s; M = m; }
        else       { S += s * __expf(m - M); }
        P = fminf(P, p);
    }
    Lm[ci][q] = M; Ls[ci][q] = S; Lp[ci][q] = P;
    __syncthreads();
    if (t < 64) {
        M = -3.4e38f; S = 0.f; P = 3.4e38f;
#pragma unroll
        for (int i = 0; i < 4; ++i) {
            float m = Lm[i][t], s = Ls[i][t], p = Lp[i][t];
            if (m > M) { S = S * __expf(M - m) + s; M = m; }
            else       { S += s * __expf(m - M); }
            P = fminf(P, p);
        }
        float Mall = fmaxf(M, P);
        float lse  = Mall + logf(S * __expf(M - Mall) + __expf(P - Mall));
        float loss = lse - P;
        for (int off = 32; off > 0; off >>= 1) loss += __shfl_down(loss, off, 64);
        if (t == 0) out[0] = loss * (1.0f / 64.0f);
    }
}

// K3: momentum update of the 64 indexed rows (last-wins on duplicates)
__global__ __launch_bounds__(256) void k_update(const float* __restrict__ feat,
                                                const float* __restrict__ f_weak,
                                                const int* __restrict__ indexes,
                                                float* __restrict__ out) {
    const int b = blockIdx.x;
    const int idx = indexes[b];
    for (int b2 = b + 1; b2 < 64; ++b2)
        if (indexes[b2] == idx) return;     // uniform over block
    const int tid = threadIdx.x;
    float wv[8];
    float ss = 0.f;
#pragma unroll
    for (int k = 0; k < 8; ++k) {
        int d = tid + 256 * k;
        float v = feat[(size_t)idx * DD + d] * 0.2f + f_weak[(size_t)b * DD + d] * 0.8f;
        wv[k] = v;
        ss += v * v;
    }
    for (int off = 32; off > 0; off >>= 1) ss += __shfl_down(ss, off, 64);
    __shared__ float red[4];
    if ((tid & 63) == 0) red[tid >> 6] = ss;
    __syncthreads();
    float tot = red[0] + red[1] + red[2] + red[3];
    float inv = 1.0f / fmaxf(sqrtf(tot), 1e-12f);
#pragma unroll
    for (int k = 0; k < 8; ++k) {
        int d = tid + 256 * k;
        out[1 + (size_t)idx * DD + d] = wv[k] * inv;
    }
}

extern "C" void kernel_launch(void* const* d_in, const int* in_sizes, int n_in,
                              void* d_out, int out_size, void* d_ws, size_t ws_size,
                              hipStream_t stream) {
    const float* f       = (const float*)d_in[0];
    const float* f_weak  = (const float*)d_in[1];
    const int*   indexes = (const int*)d_in[2];
    const float* feat    = (const float*)d_in[3];
    const int*   labels  = (const int*)d_in[4];
    float* out = (float*)d_out;
    float* ws  = (float*)d_ws;

    unsigned short* fA = (unsigned short*)ws;          // 131072 ushort
    int*   blab = (int*)(ws + 65536);
    float* Wm   = ws + 65600;
    float* Wsm  = ws + 131136;
    float* Wp   = ws + 196672;

    k_prep<<<64, 256, 0, stream>>>(f, indexes, labels, fA, blab);
    k_main<<<GRID_MAIN, 256, 0, stream>>>(feat, fA, labels, blab, out, Wm, Wsm, Wp);
    k_loss<<<1, 256, 0, stream>>>(Wm, Wsm, Wp, out);
    k_update<<<64, 256, 0, stream>>>(feat, f_weak, indexes, out);
}

// Round 4
// 348.816 us; speedup vs baseline: 1.0646x; 1.0646x over previous
//
#include <hip/hip_runtime.h>
#include <math.h>

#define DD   2048
#define TEMP 0.07f
#define GRID_MAIN 1024
#define NROWS 16          // feature rows per block
#define DC    128         // k-chunk (floats) per inner step
#define NCH   16          // chunks per row
#define CPP   8           // chunks per phase (phase = 1024 floats of k)

typedef __attribute__((ext_vector_type(8))) short short8;
typedef __attribute__((ext_vector_type(4))) float f32x4;

// ws layout (float offsets):
//   fA   [65536]  (131072 ushort: f in MFMA A-frag order [qt][ksg][lane][j])
//   blab [64]     at 65536 (int)
//   Wm   [1024*64] at 65600
//   Ws   [1024*64] at 131136
//   Wp   [1024*64] at 196672

__device__ __forceinline__ unsigned short to_bf16(float x) {
    union { float f; unsigned u; } v; v.f = x;
    unsigned r = v.u + 0x7fffu + ((v.u >> 16) & 1u);   // RNE
    return (unsigned short)(r >> 16);
}

// K0: f [64][2048] fp32 -> fA bf16 in A-fragment order; gather batch labels.
// A-frag (16x16x32): m = lane&15, k = ksg*32 + (lane>>4)*8 + j
__global__ __launch_bounds__(256) void k_prep(const float* __restrict__ f,
                                              const int* __restrict__ indexes,
                                              const int* __restrict__ labels,
                                              unsigned short* __restrict__ fA,
                                              int* __restrict__ blab) {
    const int q  = blockIdx.x;    // 0..63
    const int kc = threadIdx.x;   // k = kc*8
    const float* src = f + (size_t)q * DD + kc * 8;
    float4 a = *(const float4*)src;
    float4 b = *(const float4*)(src + 4);
    uint4 u;
    u.x = (unsigned)to_bf16(a.x) | ((unsigned)to_bf16(a.y) << 16);
    u.y = (unsigned)to_bf16(a.z) | ((unsigned)to_bf16(a.w) << 16);
    u.z = (unsigned)to_bf16(b.x) | ((unsigned)to_bf16(b.y) << 16);
    u.w = (unsigned)to_bf16(b.z) | ((unsigned)to_bf16(b.w) << 16);
    const int w = q >> 4, ksg = kc >> 2;
    const int lane = (q & 15) | ((kc & 3) << 4);
    *(uint4*)(fA + ((size_t)(w * 64 + ksg) * 64 + lane) * 8) = u;
    if (q == 0 && kc < 64) blab[kc] = labels[indexes[kc]];
}

// K1: 16 rows/block, two macro-phases over k (1024 floats each).
//  P1 (streaming): load feat (3-deep consume-replace), shuffle-realigned store
//     to out+1, bf16->LDS B-frags (XOR-swizzled) for the whole k-half.
//     NO MFMA waits inside -> loads/stores pipeline freely.
//  sync (one vmcnt drain per phase, not per chunk)
//  P2 (compute): 32 MFMAs/wave vs L2-hot fA; clean vmcnt queue.
// Epilogue: each wave owns full-k acc for its q-tile -> in-wave shfl_xor
// masked online reduce, no cross-wave combine.
__global__ __launch_bounds__(256, 4) void k_main(const float* __restrict__ feat,
                                                 const unsigned short* __restrict__ fA,
                                                 const int* __restrict__ labels,
                                                 const int* __restrict__ blab,
                                                 float* __restrict__ out,
                                                 float* __restrict__ Wm,
                                                 float* __restrict__ Ws,
                                                 float* __restrict__ Wp) {
    __shared__ uint4 Ball[32 * 64];         // B-frags for one k-half, 32 KB
    __shared__ int lab_s[16], blab_s[64];

    const int tid = threadIdx.x;
    const int w   = tid >> 6;               // wave id = q-tile
    const int l   = tid & 63;               // lane
    const int n0  = blockIdx.x * NROWS;

    if (tid < 16) lab_s[tid] = labels[n0 + tid];
    if (tid >= 64 && tid < 128) blab_s[tid - 64] = blab[tid - 64];

    const int rh = l >> 5;                  // row half within wave
    const int c  = l & 31;                  // float4 column within 128-k chunk
    const int r0_ = w * 2 + rh;             // pass p covers row p*8 + r0_
    const uint4* __restrict__ fA4 = (const uint4*)fA;

    f32x4 acc = {0.f, 0.f, 0.f, 0.f};

    // rolling 2-chunk-lookahead buffers: F[chunk parity][p]
    float4 F[2][2];
#pragma unroll
    for (int ch = 0; ch < 2; ++ch)
#pragma unroll
        for (int p = 0; p < 2; ++p)
            F[ch][p] = *(const float4*)&feat[(size_t)(n0 + p * 8 + r0_) * DD + ch * DC + 4 * c];

    // LDS write swizzle value (per-lane constant): v = (c>>1)&7
    const int vws = ((c >> 1) & 7) << 1;

    for (int ph = 0; ph < 2; ++ph) {
        if (ph > 0) __syncthreads();        // P2(ph-1) done reading Ball

        // ---------- P1: stream 8 chunks (1024 k) ----------
        for (int ch8 = 0; ch8 < CPP; ++ch8) {
            const int ch = ph * CPP + ch8;
            const int k0 = ch * DC;
#pragma unroll
            for (int p = 0; p < 2; ++p) {
                const int r = p * 8 + r0_;
                float4 Fc = F[ch & 1][p];
                if (ch + 2 < NCH)           // consume-replace prefetch
                    F[ch & 1][p] = *(const float4*)&feat[(size_t)(n0 + r) * DD + (ch + 2) * DC + 4 * c];
                // shuffle-realign: lane c stores {F.w, next.xyz} at 16B-aligned out
                float nx = __shfl_down(Fc.x, 1);
                float ny = __shfl_down(Fc.y, 1);
                float nz = __shfl_down(Fc.z, 1);
                size_t rowbase = (size_t)(n0 + r) * DD + k0;   // out[j] = feat[j-1]
                if (c < 31) {
                    *(float4*)(out + rowbase + 4 * (c + 1)) = make_float4(Fc.w, nx, ny, nz);
                } else {
                    out[rowbase + 128] = Fc.w;                 // chunk tail
                }
                if (c == 0) {                                  // chunk head (3 floats)
                    out[rowbase + 1] = Fc.x;
                    out[rowbase + 2] = Fc.y;
                    out[rowbase + 3] = Fc.z;
                }
                // bf16 -> LDS B-frag (XOR-swizzled): B[k][n], n=lane&15, k=(lane>>4)*8+j
                unsigned u0 = (unsigned)to_bf16(Fc.x) | ((unsigned)to_bf16(Fc.y) << 16);
                unsigned u1 = (unsigned)to_bf16(Fc.z) | ((unsigned)to_bf16(Fc.w) << 16);
                int ksgl  = ch8 * 4 + (c >> 3);                // local ksg 0..31
                int lanef = r | (((c >> 1) & 3) << 4);
                int I2 = (((ksgl * 64 + lanef) * 2) + (c & 1)) ^ vws;
                ((uint2*)Ball)[I2] = make_uint2(u0, u1);
            }
        }
        __syncthreads();                    // Ball complete; one drain

        // ---------- P2: 32 MFMAs vs fA (global, L2-hot) ----------
#pragma unroll 8
        for (int ksgl = 0; ksgl < 32; ++ksgl) {
            const int ksg = ph * 32 + ksgl;
            int I4 = (ksgl * 64 + l) ^ (((ksgl & 1) << 2) | ((l >> 4) & 3));
            uint4 braw = Ball[I4];
            uint4 araw = fA4[(size_t)(w * 64 + ksg) * 64 + l];
            acc = __builtin_amdgcn_mfma_f32_16x16x32_bf16(
                __builtin_bit_cast(short8, araw), __builtin_bit_cast(short8, braw), acc, 0, 0, 0);
        }
    }

    // ---- epilogue: C/D layout col(n)=lane&15, row(q in tile)=(lane>>4)*4+reg ----
    const float invT = 1.0f / TEMP;
    const int nl = l & 15;
    const int g  = l >> 4;
    const int lab = lab_s[nl];
#pragma unroll
    for (int r = 0; r < 4; ++r) {
        const int q = w * 16 + g * 4 + r;
        float y = acc[r] * invT;
        const bool match = (lab == blab_s[q]);
        float M = match ? -3.4e38f : y;
        float S = match ? 0.f : 1.f;
        float P = match ? y : 3.4e38f;
#pragma unroll
        for (int d = 1; d < 16; d <<= 1) {
            float Mo = __shfl_xor(M, d, 64);
            float So = __shfl_xor(S, d, 64);
            float Po = __shfl_xor(P, d, 64);
            float Mn = fmaxf(M, Mo);
            S = S * __expf(M - Mn) + So * __expf(Mo - Mn);
            M = Mn;
            P = fminf(P, Po);
        }
        if (nl == 0) {
            Wm[blockIdx.x * 64 + q] = M;
            Ws[blockIdx.x * 64 + q] = S;
            Wp[blockIdx.x * 64 + q] = P;
        }
    }
}

// K2: combine 1024 partials/query -> loss at out[0]
__global__ __launch_bounds__(256) void k_loss(const float* __restrict__ Wm,
                                              const float* __restrict__ Ws,
                                              const float* __restrict__ Wp,
                                              float* __restrict__ out) {
    __shared__ float Lm[4][64], Ls[4][64], Lp[4][64];
    const int t = threadIdx.x, q = t & 63, ci = t >> 6;
    float M = -3.4e38f, S = 0.f, P = 3.4e38f;
    for (int i = ci * 256; i < ci * 256 + 256; ++i) {
        float m = Wm[i * 64 + q], s = Ws[i * 64 + q], p = Wp[i * 64 + q];
        if (m > M) { S = S * __expf(M - m) + s; M = m; }
        else       { S += s * __expf(m - M); }
        P = fminf(P, p);
    }
    Lm[ci][q] = M; Ls[ci][q] = S; Lp[ci][q] = P;
    __syncthreads();
    if (t < 64) {
        M = -3.4e38f; S = 0.f; P = 3.4e38f;
#pragma unroll
        for (int i = 0; i < 4; ++i) {
            float m = Lm[i][t], s = Ls[i][t], p = Lp[i][t];
            if (m > M) { S = S * __expf(M - m) + s; M = m; }
            else       { S += s * __expf(m - M); }
            P = fminf(P, p);
        }
        float Mall = fmaxf(M, P);
        float lse  = Mall + logf(S * __expf(M - Mall) + __expf(P - Mall));
        float loss = lse - P;
        for (int off = 32; off > 0; off >>= 1) loss += __shfl_down(loss, off, 64);
        if (t == 0) out[0] = loss * (1.0f / 64.0f);
    }
}

// K3: momentum update of the 64 indexed rows (last-wins on duplicates)
__global__ __launch_bounds__(256) void k_update(const float* __restrict__ feat,
                                                const float* __restrict__ f_weak,
                                                const int* __restrict__ indexes,
                                                float* __restrict__ out) {
    const int b = blockIdx.x;
    const int idx = indexes[b];
    for (int b2 = b + 1; b2 < 64; ++b2)
        if (indexes[b2] == idx) return;     // uniform over block
    const int tid = threadIdx.x;
    float wv[8];
    float ss = 0.f;
#pragma unroll
    for (int k = 0; k < 8; ++k) {
        int d = tid + 256 * k;
        float v = feat[(size_t)idx * DD + d] * 0.2f + f_weak[(size_t)b * DD + d] * 0.8f;
        wv[k] = v;
        ss += v * v;
    }
    for (int off = 32; off > 0; off >>= 1) ss += __shfl_down(ss, off, 64);
    __shared__ float red[4];
    if ((tid & 63) == 0) red[tid >> 6] = ss;
    __syncthreads();
    float tot = red[0] + red[1] + red[2] + red[3];
    float inv = 1.0f / fmaxf(sqrtf(tot), 1e-12f);
#pragma unroll
    for (int k = 0; k < 8; ++k) {
        int d = tid + 256 * k;
        out[1 + (size_t)idx * DD + d] = wv[k] * inv;
    }
}

extern "C" void kernel_launch(void* const* d_in, const int* in_sizes, int n_in,
                              void* d_out, int out_size, void* d_ws, size_t ws_size,
                              hipStream_t stream) {
    const float* f       = (const float*)d_in[0];
    const float* f_weak  = (const float*)d_in[1];
    const int*   indexes = (const int*)d_in[2];
    const float* feat    = (const float*)d_in[3];
    const int*   labels  = (const int*)d_in[4];
    float* out = (float*)d_out;
    float* ws  = (float*)d_ws;

    unsigned short* fA = (unsigned short*)ws;          // 131072 ushort
    int*   blab = (int*)(ws + 65536);
    float* Wm   = ws + 65600;
    float* Wsm  = ws + 131136;
    float* Wp   = ws + 196672;

    k_prep<<<64, 256, 0, stream>>>(f, indexes, labels, fA, blab);
    k_main<<<GRID_MAIN, 256, 0, stream>>>(feat, fA, labels, blab, out, Wm, Wsm, Wp);
    k_loss<<<1, 256, 0, stream>>>(Wm, Wsm, Wp, out);
    k_update<<<64, 256, 0, stream>>>(feat, f_weak, indexes, out);
}